// Round 6
// baseline (138.816 us; speedup 1.0000x reference)
//
#include <hip/hip_runtime.h>
#include <math.h>

#define M_ROWS 1536
#define NC 96
#define KG 16
#define FD 8192
#define NS 8
#define MARGIN 0.3f

#define KSPLIT 32
#define KCH 256            /* k per block */
#define BKS 32             /* k per stage */
#define NST (KCH / BKS)    /* 8 stages */
#define BN6 64             /* n cols per block */
#define AST6 36            /* padded LDS strides (floats) */
#define BST6 36

// ---------------- K1: centers + squared-norm partials ----------------
__global__ void centers_kernel(const float* __restrict__ feats,
                               float* __restrict__ centers,
                               float* __restrict__ fnp,   // [4][1536]
                               float* __restrict__ cnp) { // [4][96]
    const int c = blockIdx.x;
    const int bd = blockIdx.y;
    const int tid = threadIdx.x;

    float sq[KG];
#pragma unroll
    for (int k = 0; k < KG; ++k) sq[k] = 0.f;
    float cp = 0.f;

#pragma unroll
    for (int it = 0; it < 2; ++it) {
        const int base = bd * 2048 + it * 1024 + tid * 4;
        float4 acc = make_float4(0.f, 0.f, 0.f, 0.f);
#pragma unroll
        for (int k = 0; k < KG; ++k) {
            const float4 v = *(const float4*)&feats[(size_t)(c * KG + k) * FD + base];
            acc.x += v.x; acc.y += v.y; acc.z += v.z; acc.w += v.w;
            sq[k] += v.x * v.x + v.y * v.y + v.z * v.z + v.w * v.w;
        }
        float4 cv = make_float4(acc.x * 0.0625f, acc.y * 0.0625f,
                                acc.z * 0.0625f, acc.w * 0.0625f);
        *(float4*)&centers[(size_t)c * FD + base] = cv;
        cp += cv.x * cv.x + cv.y * cv.y + cv.z * cv.z + cv.w * cv.w;
    }

    const int lane = tid & 63;
    const int w = tid >> 6;
    __shared__ float wred[4][17];
#pragma unroll
    for (int k = 0; k < KG; ++k) {
        float v = sq[k];
#pragma unroll
        for (int off = 32; off > 0; off >>= 1) v += __shfl_down(v, off, 64);
        if (lane == 0) wred[w][k] = v;
    }
    {
        float v = cp;
#pragma unroll
        for (int off = 32; off > 0; off >>= 1) v += __shfl_down(v, off, 64);
        if (lane == 0) wred[w][16] = v;
    }
    __syncthreads();
    if (tid < 17) {
        const float t = wred[0][tid] + wred[1][tid] + wred[2][tid] + wred[3][tid];
        if (tid < 16) fnp[bd * M_ROWS + c * KG + tid] = t;
        else          cnp[bd * NC + c] = t;
    }
}

// ---------------- K2: dot(center, feat) partial GEMM ----------------
// 768 blocks, bid = nb*32 + ks; bid%8 == ks%8 pins a k-slice to one XCD.
// 256 threads, 6m x 4n acc. No min-waves bound (R3/R4: forced VGPR=64 ->
// spill -> 1.2 GB traffic). R6 change: DOUBLE-BUFFERED LDS, one barrier
// per stage (R5 had two) -- compute starts right after the barrier and the
// prefetch vmcnt-wait lands after the compute block.
__global__ __launch_bounds__(256) void gemm6_kernel(const float* __restrict__ centers,
                                                    const float* __restrict__ feats,
                                                    float* __restrict__ part) { // [96][32][1536]
    const int bid = blockIdx.x;
    const int ks = bid & 31;
    const int nb = bid >> 5;
    const int tid = threadIdx.x;

    __shared__ float alds[2][NC * AST6];
    __shared__ float blds[2][BN6 * BST6];

    const int j0 = nb * BN6;
    const int k0b = ks * KCH;

    const int tx = tid & 15;         // n = tx + 16*nn, nn 0..3
    const int ty = tid >> 4;         // m = ty*6 + mi, mi 0..5
    const int m0 = ty * 6;

    // staging addresses: A rows am, am+32, am+64; B rows bn, bn+32
    const int am = tid >> 3;
    const int akk = (tid & 7) * 4;
    const int bn = tid >> 3;

    float4 pa[3], pb[2];

    {   // prologue: stage 0 -> regs -> lds[0]
        const int k0 = k0b;
#pragma unroll
        for (int i = 0; i < 3; ++i)
            pa[i] = *(const float4*)&centers[(size_t)(am + i * 32) * FD + k0 + akk];
#pragma unroll
        for (int i = 0; i < 2; ++i)
            pb[i] = *(const float4*)&feats[(size_t)(j0 + bn + i * 32) * FD + k0 + akk];
#pragma unroll
        for (int i = 0; i < 3; ++i)
            *(float4*)&alds[0][(am + i * 32) * AST6 + akk] = pa[i];
#pragma unroll
        for (int i = 0; i < 2; ++i)
            *(float4*)&blds[0][(bn + i * 32) * BST6 + akk] = pb[i];
    }
    __syncthreads();

    float acc[6][4];
#pragma unroll
    for (int a = 0; a < 6; ++a)
#pragma unroll
        for (int b = 0; b < 4; ++b) acc[a][b] = 0.f;

    for (int st = 0; st < NST; ++st) {
        const int cur = st & 1;

        // issue next stage's global loads; they fly during compute below
        if (st < NST - 1) {
            const int k0 = k0b + (st + 1) * BKS;
#pragma unroll
            for (int i = 0; i < 3; ++i)
                pa[i] = *(const float4*)&centers[(size_t)(am + i * 32) * FD + k0 + akk];
#pragma unroll
            for (int i = 0; i < 2; ++i)
                pb[i] = *(const float4*)&feats[(size_t)(j0 + bn + i * 32) * FD + k0 + akk];
        }

        // compute current buffer
#pragma unroll
        for (int kk4 = 0; kk4 < BKS; kk4 += 4) {
            float4 bv[4];
#pragma unroll
            for (int nn = 0; nn < 4; ++nn)
                bv[nn] = *(const float4*)&blds[cur][(tx + nn * 16) * BST6 + kk4];
#pragma unroll
            for (int mi = 0; mi < 6; ++mi) {
                const float4 a = *(const float4*)&alds[cur][(m0 + mi) * AST6 + kk4];
#pragma unroll
                for (int nn = 0; nn < 4; ++nn)
                    acc[mi][nn] += a.x * bv[nn].x + a.y * bv[nn].y +
                                   a.z * bv[nn].z + a.w * bv[nn].w;
            }
        }

        // write next stage into the other buffer (prev stage's readers are
        // past the last barrier, so buf cur^1 is free)
        if (st < NST - 1) {
#pragma unroll
            for (int i = 0; i < 3; ++i)
                *(float4*)&alds[cur ^ 1][(am + i * 32) * AST6 + akk] = pa[i];
#pragma unroll
            for (int i = 0; i < 2; ++i)
                *(float4*)&blds[cur ^ 1][(bn + i * 32) * BST6 + akk] = pb[i];
        }
        __syncthreads();
    }

#pragma unroll
    for (int mi = 0; mi < 6; ++mi) {
        float* row = part + ((size_t)(m0 + mi) * KSPLIT + ks) * M_ROWS + j0;
#pragma unroll
        for (int nn = 0; nn < 4; ++nn)
            row[tx + nn * 16] = acc[mi][nn];
    }
}

// ---------------- K3: finalize d2 + masked argmax/argmin ----------------
__global__ void select_kernel(const float* __restrict__ part,
                              const float* __restrict__ fnp,
                              const float* __restrict__ cnp,
                              const int* __restrict__ labels,
                              int* __restrict__ pinds,
                              int* __restrict__ ninds) {
    const int c = blockIdx.x;
    const int tid = threadIdx.x;
    const int anchor = labels[c * KG];

    float cn = 0.f;
#pragma unroll
    for (int b = 0; b < 4; ++b) cn += cnp[b * NC + c];

    float bestp = -INFINITY; int bpi = 1 << 30;
    float bestn =  INFINITY; int bni = 1 << 30;

    const float* pc = part + (size_t)c * KSPLIT * M_ROWS;
    for (int j = tid; j < M_ROWS; j += 256) {
        float dot = 0.f;
#pragma unroll
        for (int p = 0; p < KSPLIT; ++p)
            dot += pc[(size_t)p * M_ROWS + j];
        float fn = 0.f;
#pragma unroll
        for (int b = 0; b < 4; ++b) fn += fnp[b * M_ROWS + j];
        const float d2 = cn + fn - 2.f * dot;
        const bool pos = (labels[j] == anchor);
        if (pos) {
            if (d2 > bestp || (d2 == bestp && j < bpi)) { bestp = d2; bpi = j; }
        } else {
            if (d2 < bestn || (d2 == bestn && j < bni)) { bestn = d2; bni = j; }
        }
    }

    __shared__ float sv[256];
    __shared__ int   si[256];
    sv[tid] = bestp; si[tid] = bpi; __syncthreads();
    for (int s = 128; s > 0; s >>= 1) {
        if (tid < s) {
            if (sv[tid + s] > sv[tid] ||
                (sv[tid + s] == sv[tid] && si[tid + s] < si[tid])) {
                sv[tid] = sv[tid + s]; si[tid] = si[tid + s];
            }
        }
        __syncthreads();
    }
    if (tid == 0) pinds[c] = si[0];
    __syncthreads();
    sv[tid] = bestn; si[tid] = bni; __syncthreads();
    for (int s = 128; s > 0; s >>= 1) {
        if (tid < s) {
            if (sv[tid + s] < sv[tid] ||
                (sv[tid + s] == sv[tid] && si[tid + s] < si[tid])) {
                sv[tid] = sv[tid + s]; si[tid] = si[tid + s];
            }
        }
        __syncthreads();
    }
    if (tid == 0) ninds[c] = si[0];
}

// ---------------- K4: local stripe distances + DP ----------------
__global__ void local_kernel(const float* __restrict__ centers,
                             const float* __restrict__ localf,
                             const int* __restrict__ pinds,
                             const int* __restrict__ ninds,
                             float* __restrict__ res) { // [2][96]
    const int c = blockIdx.x;
    const int which = blockIdx.y;
    const int tid = threadIdx.x;
    const int idx = (which == 0) ? pinds[c] : ninds[c];

    __shared__ float xl[NS * 1028];
    __shared__ float yl[NS * 1032];
    __shared__ float sred[256];
    __shared__ float dmat[64];
    __shared__ float xx[8], yy[8], xyv[64];

#pragma unroll
    for (int it = 0; it < 8; ++it) {
        const int q = tid + it * 256;
        const float4 v = *(const float4*)&centers[(size_t)c * FD + q * 4];
        const int i = q >> 8;
        const int d = (q * 4) & 1023;
        *(float4*)&xl[i * 1028 + d] = v;

        const float4 w = *(const float4*)&localf[(size_t)idx * FD + q * 4];
        const int jb = (q * 4) & 7;
        const int dd = q >> 1;
        yl[(jb + 0) * 1032 + dd] = w.x;
        yl[(jb + 1) * 1032 + dd] = w.y;
        yl[(jb + 2) * 1032 + dd] = w.z;
        yl[(jb + 3) * 1032 + dd] = w.w;
    }
    __syncthreads();

    const int p = tid >> 2, c4 = tid & 3;
    const int i = p >> 3, j = p & 7;
    float s = 0.f;
    for (int t = 0; t < 64; ++t) {
        const int d = c4 * 4 + t * 16;
        const float4 xv = *(const float4*)&xl[i * 1028 + d];
        const float4 yv = *(const float4*)&yl[j * 1032 + d];
        s += xv.x * yv.x + xv.y * yv.y + xv.z * yv.z + xv.w * yv.w;
    }
    sred[tid] = s;
    __syncthreads();
    if (tid < 64)
        xyv[tid] = sred[tid * 4] + sred[tid * 4 + 1] + sred[tid * 4 + 2] + sred[tid * 4 + 3];

    float s2 = 0.f;
    if (tid < 64) {
        const int r = tid >> 2;
        const float* base = (r < 8) ? &xl[r * 1028] : &yl[(r - 8) * 1032];
        for (int t = 0; t < 64; ++t) {
            const int d = c4 * 4 + t * 16;
            const float4 v = *(const float4*)&base[d];
            s2 += v.x * v.x + v.y * v.y + v.z * v.z + v.w * v.w;
        }
    }
    __syncthreads();
    sred[tid] = s2;
    __syncthreads();
    if (tid < 16) {
        const float v = sred[tid * 4] + sred[tid * 4 + 1] + sred[tid * 4 + 2] + sred[tid * 4 + 3];
        if (tid < 8) xx[tid] = v; else yy[tid - 8] = v;
    }
    __syncthreads();

    if (tid < 64) {
        const float d2 = xx[i] + yy[j] - 2.f * xyv[tid];
        const float d = sqrtf(fmaxf(d2, 1e-12f));
        dmat[tid] = tanhf(0.5f * d);
    }
    __syncthreads();

    if (tid == 0) {
        float prev[8], cur[8];
        cur[0] = dmat[0];
#pragma unroll
        for (int jj = 1; jj < 8; ++jj) cur[jj] = cur[jj - 1] + dmat[jj];
        for (int ii = 1; ii < 8; ++ii) {
#pragma unroll
            for (int jj = 0; jj < 8; ++jj) prev[jj] = cur[jj];
            cur[0] = prev[0] + dmat[ii * 8];
#pragma unroll
            for (int jj = 1; jj < 8; ++jj)
                cur[jj] = fminf(prev[jj], cur[jj - 1]) + dmat[ii * 8 + jj];
        }
        res[which * NC + c] = cur[7];
    }
}

// ---------------- K5: mean(relu(ap - an + margin)) ----------------
__global__ void loss_kernel(const float* __restrict__ res, float* __restrict__ out) {
    const int tid = threadIdx.x; // 128
    float v = 0.f;
    if (tid < NC) v = fmaxf(res[tid] - res[NC + tid] + MARGIN, 0.f);
#pragma unroll
    for (int off = 32; off > 0; off >>= 1) v += __shfl_down(v, off, 64);
    __shared__ float w2[2];
    const int lane = tid & 63, w = tid >> 6;
    if (lane == 0) w2[w] = v;
    __syncthreads();
    if (tid == 0) out[0] = (w2[0] + w2[1]) * (1.f / NC);
}

extern "C" void kernel_launch(void* const* d_in, const int* in_sizes, int n_in,
                              void* d_out, int out_size, void* d_ws, size_t ws_size,
                              hipStream_t stream) {
    const float* feats  = (const float*)d_in[0];
    const int*   labels = (const int*)d_in[1];
    const float* localf = (const float*)d_in[2];
    float* out = (float*)d_out;

    float* centers = (float*)d_ws;                          // 96*8192
    float* part    = centers + (size_t)NC * FD;             // 96*32*1536
    float* fnp     = part + (size_t)NC * KSPLIT * M_ROWS;   // 4*1536
    float* cnp     = fnp + 4 * M_ROWS;                      // 4*96
    float* res     = cnp + 4 * NC;                          // 2*96
    int*   pinds   = (int*)(res + 2 * NC);                  // 96
    int*   ninds   = pinds + NC;                            // 96

    hipLaunchKernelGGL(centers_kernel, dim3(NC, 4), dim3(256), 0, stream,
                       feats, centers, fnp, cnp);
    hipLaunchKernelGGL(gemm6_kernel, dim3(24 * KSPLIT), dim3(256), 0, stream,
                       centers, feats, part);
    hipLaunchKernelGGL(select_kernel, dim3(NC), dim3(256), 0, stream,
                       part, fnp, cnp, labels, pinds, ninds);
    hipLaunchKernelGGL(local_kernel, dim3(NC, 2), dim3(256), 0, stream,
                       centers, localf, pinds, ninds, res);
    hipLaunchKernelGGL(loss_kernel, dim3(1), dim3(128), 0, stream, res, out);
}

// Round 7
// 112.582 us; speedup vs baseline: 1.2330x; 1.2330x over previous
//
#include <hip/hip_runtime.h>
#include <math.h>

#define M_ROWS 1536
#define NC 96
#define KG 16
#define FD 8192
#define NS 8
#define MARGIN 0.3f

#define KSPLIT 32
#define KCH 256            /* k per block */
#define BKS 32             /* k per stage */
#define NST (KCH / BKS)    /* 8 stages */
#define BN7 64             /* n cols per block */

// async global->LDS, 16B per lane (dest = wave-uniform base + lane*16)
__device__ __forceinline__ void gload16(const float* g, float* lds) {
    __builtin_amdgcn_global_load_lds(
        (const __attribute__((address_space(1))) void*)g,
        (__attribute__((address_space(3))) void*)lds, 16, 0, 0);
}

// ---------------- K1: centers + squared-norm partials ----------------
__global__ void centers_kernel(const float* __restrict__ feats,
                               float* __restrict__ centers,
                               float* __restrict__ fnp,   // [4][1536]
                               float* __restrict__ cnp) { // [4][96]
    const int c = blockIdx.x;
    const int bd = blockIdx.y;
    const int tid = threadIdx.x;

    float sq[KG];
#pragma unroll
    for (int k = 0; k < KG; ++k) sq[k] = 0.f;
    float cp = 0.f;

#pragma unroll
    for (int it = 0; it < 2; ++it) {
        const int base = bd * 2048 + it * 1024 + tid * 4;
        float4 acc = make_float4(0.f, 0.f, 0.f, 0.f);
#pragma unroll
        for (int k = 0; k < KG; ++k) {
            const float4 v = *(const float4*)&feats[(size_t)(c * KG + k) * FD + base];
            acc.x += v.x; acc.y += v.y; acc.z += v.z; acc.w += v.w;
            sq[k] += v.x * v.x + v.y * v.y + v.z * v.z + v.w * v.w;
        }
        float4 cv = make_float4(acc.x * 0.0625f, acc.y * 0.0625f,
                                acc.z * 0.0625f, acc.w * 0.0625f);
        *(float4*)&centers[(size_t)c * FD + base] = cv;
        cp += cv.x * cv.x + cv.y * cv.y + cv.z * cv.z + cv.w * cv.w;
    }

    const int lane = tid & 63;
    const int w = tid >> 6;
    __shared__ float wred[4][17];
#pragma unroll
    for (int k = 0; k < KG; ++k) {
        float v = sq[k];
#pragma unroll
        for (int off = 32; off > 0; off >>= 1) v += __shfl_down(v, off, 64);
        if (lane == 0) wred[w][k] = v;
    }
    {
        float v = cp;
#pragma unroll
        for (int off = 32; off > 0; off >>= 1) v += __shfl_down(v, off, 64);
        if (lane == 0) wred[w][16] = v;
    }
    __syncthreads();
    if (tid < 17) {
        const float t = wred[0][tid] + wred[1][tid] + wred[2][tid] + wred[3][tid];
        if (tid < 16) fnp[bd * M_ROWS + c * KG + tid] = t;
        else          cnp[bd * NC + c] = t;
    }
}

// ---------------- K2: dot(center, feat) partial GEMM ----------------
// 768 blocks, bid = nb*32 + ks; bid%8 == ks%8 pins a k-slice to one XCD.
// R7: staging via global_load_lds (async DMA, no reg round-trip, no
// ds_writes), LDS double-buffered 2x20KB LINEAR (DMA requires it),
// k-group-major layout (slot = kkg*ROWS + row) so reads spread banks by
// row&7 -> conflict-free without padding. ONE barrier per stage; the
// __syncthreads vmcnt(0) drain guarantees the DMA landed.
__global__ __launch_bounds__(256) void gemm7_kernel(const float* __restrict__ centers,
                                                    const float* __restrict__ feats,
                                                    float* __restrict__ part) { // [96][32][1536]
    const int bid = blockIdx.x;
    const int ks = bid & 31;
    const int nb = bid >> 5;
    const int tid = threadIdx.x;

    __shared__ float alds[2][NST * NC * 4];   // [kkg][96] float4 slots
    __shared__ float blds[2][NST * BN7 * 4];  // [kkg][64] float4 slots

    const int j0 = nb * BN7;
    const int k0b = ks * KCH;

    const int tx = tid & 15;         // n = tx + 16*nn, nn 0..3
    const int ty = tid >> 4;         // m = ty*6 + mi, mi 0..5
    const int m0 = ty * 6;

    // per-lane DMA source mapping (computed once; only k0 varies per stage)
    // A slots: s = tid + i*256, s = kkg*96 + m
    const float* aga[3];
    int albase[3];
#pragma unroll
    for (int i = 0; i < 3; ++i) {
        const int s = tid + i * 256;
        const int kkg = s / NC, m = s - kkg * NC;
        aga[i] = centers + (size_t)m * FD + kkg * 4;
        albase[i] = (i * 256 + (tid & 192)) * 4;   // float offset of wave chunk
    }
    // B slots: s = tid + i*256, s = kkg*64 + n
    const float* bga[2];
    int blbase[2];
#pragma unroll
    for (int i = 0; i < 2; ++i) {
        const int s = tid + i * 256;
        const int kkg = s >> 6, n = s & 63;
        bga[i] = feats + (size_t)(j0 + n) * FD + kkg * 4;
        blbase[i] = (i * 256 + (tid & 192)) * 4;
    }

    // prologue: stage 0 -> buf 0
#pragma unroll
    for (int i = 0; i < 3; ++i) gload16(aga[i] + k0b, &alds[0][albase[i]]);
#pragma unroll
    for (int i = 0; i < 2; ++i) gload16(bga[i] + k0b, &blds[0][blbase[i]]);
    __syncthreads();

    float acc[6][4];
#pragma unroll
    for (int a = 0; a < 6; ++a)
#pragma unroll
        for (int b = 0; b < 4; ++b) acc[a][b] = 0.f;

    int cur = 0;
    for (int st = 0; st < NST; ++st) {
        // issue next stage's DMA into the other buffer; flies during compute
        if (st < NST - 1) {
            const int k0 = k0b + (st + 1) * BKS;
#pragma unroll
            for (int i = 0; i < 3; ++i) gload16(aga[i] + k0, &alds[cur ^ 1][albase[i]]);
#pragma unroll
            for (int i = 0; i < 2; ++i) gload16(bga[i] + k0, &blds[cur ^ 1][blbase[i]]);
        }

        // compute current buffer: k-group-major, conflict-free reads
#pragma unroll
        for (int kg = 0; kg < NST; ++kg) {
            const float* ab = &alds[cur][kg * (NC * 4)];
            const float* bb = &blds[cur][kg * (BN7 * 4)];
            float4 bv[4];
#pragma unroll
            for (int nn = 0; nn < 4; ++nn)
                bv[nn] = *(const float4*)&bb[(tx + nn * 16) * 4];
#pragma unroll
            for (int mi = 0; mi < 6; ++mi) {
                const float4 a = *(const float4*)&ab[(m0 + mi) * 4];
#pragma unroll
                for (int nn = 0; nn < 4; ++nn)
                    acc[mi][nn] += a.x * bv[nn].x + a.y * bv[nn].y +
                                   a.z * bv[nn].z + a.w * bv[nn].w;
            }
        }
        __syncthreads();   // drains vmcnt -> next buffer ready
        cur ^= 1;
    }

#pragma unroll
    for (int mi = 0; mi < 6; ++mi) {
        float* row = part + ((size_t)(m0 + mi) * KSPLIT + ks) * M_ROWS + j0;
#pragma unroll
        for (int nn = 0; nn < 4; ++nn)
            row[tx + nn * 16] = acc[mi][nn];
    }
}

// ---------------- K3: finalize d2 + masked argmax/argmin ----------------
__global__ void select_kernel(const float* __restrict__ part,
                              const float* __restrict__ fnp,
                              const float* __restrict__ cnp,
                              const int* __restrict__ labels,
                              int* __restrict__ pinds,
                              int* __restrict__ ninds) {
    const int c = blockIdx.x;
    const int tid = threadIdx.x;
    const int anchor = labels[c * KG];

    float cn = 0.f;
#pragma unroll
    for (int b = 0; b < 4; ++b) cn += cnp[b * NC + c];

    float bestp = -INFINITY; int bpi = 1 << 30;
    float bestn =  INFINITY; int bni = 1 << 30;

    const float* pc = part + (size_t)c * KSPLIT * M_ROWS;
    for (int j = tid; j < M_ROWS; j += 256) {
        float dot = 0.f;
#pragma unroll
        for (int p = 0; p < KSPLIT; ++p)
            dot += pc[(size_t)p * M_ROWS + j];
        float fn = 0.f;
#pragma unroll
        for (int b = 0; b < 4; ++b) fn += fnp[b * M_ROWS + j];
        const float d2 = cn + fn - 2.f * dot;
        const bool pos = (labels[j] == anchor);
        if (pos) {
            if (d2 > bestp || (d2 == bestp && j < bpi)) { bestp = d2; bpi = j; }
        } else {
            if (d2 < bestn || (d2 == bestn && j < bni)) { bestn = d2; bni = j; }
        }
    }

    __shared__ float sv[256];
    __shared__ int   si[256];
    sv[tid] = bestp; si[tid] = bpi; __syncthreads();
    for (int s = 128; s > 0; s >>= 1) {
        if (tid < s) {
            if (sv[tid + s] > sv[tid] ||
                (sv[tid + s] == sv[tid] && si[tid + s] < si[tid])) {
                sv[tid] = sv[tid + s]; si[tid] = si[tid + s];
            }
        }
        __syncthreads();
    }
    if (tid == 0) pinds[c] = si[0];
    __syncthreads();
    sv[tid] = bestn; si[tid] = bni; __syncthreads();
    for (int s = 128; s > 0; s >>= 1) {
        if (tid < s) {
            if (sv[tid + s] < sv[tid] ||
                (sv[tid + s] == sv[tid] && si[tid + s] < si[tid])) {
                sv[tid] = sv[tid + s]; si[tid] = si[tid + s];
            }
        }
        __syncthreads();
    }
    if (tid == 0) ninds[c] = si[0];
}

// ---------------- K4: local stripe distances + DP ----------------
__global__ void local_kernel(const float* __restrict__ centers,
                             const float* __restrict__ localf,
                             const int* __restrict__ pinds,
                             const int* __restrict__ ninds,
                             float* __restrict__ res) { // [2][96]
    const int c = blockIdx.x;
    const int which = blockIdx.y;
    const int tid = threadIdx.x;
    const int idx = (which == 0) ? pinds[c] : ninds[c];

    __shared__ float xl[NS * 1028];
    __shared__ float yl[NS * 1032];
    __shared__ float sred[256];
    __shared__ float dmat[64];
    __shared__ float xx[8], yy[8], xyv[64];

#pragma unroll
    for (int it = 0; it < 8; ++it) {
        const int q = tid + it * 256;
        const float4 v = *(const float4*)&centers[(size_t)c * FD + q * 4];
        const int i = q >> 8;
        const int d = (q * 4) & 1023;
        *(float4*)&xl[i * 1028 + d] = v;

        const float4 w = *(const float4*)&localf[(size_t)idx * FD + q * 4];
        const int jb = (q * 4) & 7;
        const int dd = q >> 1;
        yl[(jb + 0) * 1032 + dd] = w.x;
        yl[(jb + 1) * 1032 + dd] = w.y;
        yl[(jb + 2) * 1032 + dd] = w.z;
        yl[(jb + 3) * 1032 + dd] = w.w;
    }
    __syncthreads();

    const int p = tid >> 2, c4 = tid & 3;
    const int i = p >> 3, j = p & 7;
    float s = 0.f;
    for (int t = 0; t < 64; ++t) {
        const int d = c4 * 4 + t * 16;
        const float4 xv = *(const float4*)&xl[i * 1028 + d];
        const float4 yv = *(const float4*)&yl[j * 1032 + d];
        s += xv.x * yv.x + xv.y * yv.y + xv.z * yv.z + xv.w * yv.w;
    }
    sred[tid] = s;
    __syncthreads();
    if (tid < 64)
        xyv[tid] = sred[tid * 4] + sred[tid * 4 + 1] + sred[tid * 4 + 2] + sred[tid * 4 + 3];

    float s2 = 0.f;
    if (tid < 64) {
        const int r = tid >> 2;
        const float* base = (r < 8) ? &xl[r * 1028] : &yl[(r - 8) * 1032];
        for (int t = 0; t < 64; ++t) {
            const int d = c4 * 4 + t * 16;
            const float4 v = *(const float4*)&base[d];
            s2 += v.x * v.x + v.y * v.y + v.z * v.z + v.w * v.w;
        }
    }
    __syncthreads();
    sred[tid] = s2;
    __syncthreads();
    if (tid < 16) {
        const float v = sred[tid * 4] + sred[tid * 4 + 1] + sred[tid * 4 + 2] + sred[tid * 4 + 3];
        if (tid < 8) xx[tid] = v; else yy[tid - 8] = v;
    }
    __syncthreads();

    if (tid < 64) {
        const float d2 = xx[i] + yy[j] - 2.f * xyv[tid];
        const float d = sqrtf(fmaxf(d2, 1e-12f));
        dmat[tid] = tanhf(0.5f * d);
    }
    __syncthreads();

    if (tid == 0) {
        float prev[8], cur[8];
        cur[0] = dmat[0];
#pragma unroll
        for (int jj = 1; jj < 8; ++jj) cur[jj] = cur[jj - 1] + dmat[jj];
        for (int ii = 1; ii < 8; ++ii) {
#pragma unroll
            for (int jj = 0; jj < 8; ++jj) prev[jj] = cur[jj];
            cur[0] = prev[0] + dmat[ii * 8];
#pragma unroll
            for (int jj = 1; jj < 8; ++jj)
                cur[jj] = fminf(prev[jj], cur[jj - 1]) + dmat[ii * 8 + jj];
        }
        res[which * NC + c] = cur[7];
    }
}

// ---------------- K5: mean(relu(ap - an + margin)) ----------------
__global__ void loss_kernel(const float* __restrict__ res, float* __restrict__ out) {
    const int tid = threadIdx.x; // 128
    float v = 0.f;
    if (tid < NC) v = fmaxf(res[tid] - res[NC + tid] + MARGIN, 0.f);
#pragma unroll
    for (int off = 32; off > 0; off >>= 1) v += __shfl_down(v, off, 64);
    __shared__ float w2[2];
    const int lane = tid & 63, w = tid >> 6;
    if (lane == 0) w2[w] = v;
    __syncthreads();
    if (tid == 0) out[0] = (w2[0] + w2[1]) * (1.f / NC);
}

extern "C" void kernel_launch(void* const* d_in, const int* in_sizes, int n_in,
                              void* d_out, int out_size, void* d_ws, size_t ws_size,
                              hipStream_t stream) {
    const float* feats  = (const float*)d_in[0];
    const int*   labels = (const int*)d_in[1];
    const float* localf = (const float*)d_in[2];
    float* out = (float*)d_out;

    float* centers = (float*)d_ws;                          // 96*8192
    float* part    = centers + (size_t)NC * FD;             // 96*32*1536
    float* fnp     = part + (size_t)NC * KSPLIT * M_ROWS;   // 4*1536
    float* cnp     = fnp + 4 * M_ROWS;                      // 4*96
    float* res     = cnp + 4 * NC;                          // 2*96
    int*   pinds   = (int*)(res + 2 * NC);                  // 96
    int*   ninds   = pinds + NC;                            // 96

    hipLaunchKernelGGL(centers_kernel, dim3(NC, 4), dim3(256), 0, stream,
                       feats, centers, fnp, cnp);
    hipLaunchKernelGGL(gemm7_kernel, dim3(24 * KSPLIT), dim3(256), 0, stream,
                       centers, feats, part);
    hipLaunchKernelGGL(select_kernel, dim3(NC), dim3(256), 0, stream,
                       part, fnp, cnp, labels, pinds, ninds);
    hipLaunchKernelGGL(local_kernel, dim3(NC, 2), dim3(256), 0, stream,
                       centers, localf, pinds, ninds, res);
    hipLaunchKernelGGL(loss_kernel, dim3(1), dim3(128), 0, stream, res, out);
}

// Round 8
// 107.876 us; speedup vs baseline: 1.2868x; 1.0436x over previous
//
#include <hip/hip_runtime.h>
#include <math.h>

#define M_ROWS 1536
#define NC 96
#define KG 16
#define FD 8192
#define NS 8
#define MARGIN 0.3f

#define KSPLIT 32
#define KCH 256            /* k per block */
#define BKS 32             /* k per stage */
#define NST (KCH / BKS)    /* 8 stages */
#define BN8 96             /* n cols per block */

// async global->LDS, 16B per lane (dest = wave-uniform base + lane*16)
__device__ __forceinline__ void gload16(const float* g, float* lds) {
    __builtin_amdgcn_global_load_lds(
        (const __attribute__((address_space(1))) void*)g,
        (__attribute__((address_space(3))) void*)lds, 16, 0, 0);
}

// ---------------- K1: centers + squared-norm partials ----------------
__global__ void centers_kernel(const float* __restrict__ feats,
                               float* __restrict__ centers,
                               float* __restrict__ fnp,   // [4][1536]
                               float* __restrict__ cnp) { // [4][96]
    const int c = blockIdx.x;
    const int bd = blockIdx.y;
    const int tid = threadIdx.x;

    float sq[KG];
#pragma unroll
    for (int k = 0; k < KG; ++k) sq[k] = 0.f;
    float cp = 0.f;

#pragma unroll
    for (int it = 0; it < 2; ++it) {
        const int base = bd * 2048 + it * 1024 + tid * 4;
        float4 acc = make_float4(0.f, 0.f, 0.f, 0.f);
#pragma unroll
        for (int k = 0; k < KG; ++k) {
            const float4 v = *(const float4*)&feats[(size_t)(c * KG + k) * FD + base];
            acc.x += v.x; acc.y += v.y; acc.z += v.z; acc.w += v.w;
            sq[k] += v.x * v.x + v.y * v.y + v.z * v.z + v.w * v.w;
        }
        float4 cv = make_float4(acc.x * 0.0625f, acc.y * 0.0625f,
                                acc.z * 0.0625f, acc.w * 0.0625f);
        *(float4*)&centers[(size_t)c * FD + base] = cv;
        cp += cv.x * cv.x + cv.y * cv.y + cv.z * cv.z + cv.w * cv.w;
    }

    const int lane = tid & 63;
    const int w = tid >> 6;
    __shared__ float wred[4][17];
#pragma unroll
    for (int k = 0; k < KG; ++k) {
        float v = sq[k];
#pragma unroll
        for (int off = 32; off > 0; off >>= 1) v += __shfl_down(v, off, 64);
        if (lane == 0) wred[w][k] = v;
    }
    {
        float v = cp;
#pragma unroll
        for (int off = 32; off > 0; off >>= 1) v += __shfl_down(v, off, 64);
        if (lane == 0) wred[w][16] = v;
    }
    __syncthreads();
    if (tid < 17) {
        const float t = wred[0][tid] + wred[1][tid] + wred[2][tid] + wred[3][tid];
        if (tid < 16) fnp[bd * M_ROWS + c * KG + tid] = t;
        else          cnp[bd * NC + c] = t;
    }
}

// ---------------- K2: dot(center, feat) partial GEMM ----------------
// R8: 512 blocks (16 n-tiles x 32 k-slices) = EXACTLY 2 blocks/CU = the
// 2-blocks/CU VGPR co-residency cap -> single round, no tail (R7's 768
// blocks ran 1.5 rounds). bid%8 == ks%8 pins k-slices to XCDs. 256 thr,
// 6m x 6n acc (36). DMA staging, double-buffered linear LDS (2x24KB),
// k-group-major slots (slot = kkg*96 + row), one barrier per stage.
__global__ __launch_bounds__(256) void gemm8_kernel(const float* __restrict__ centers,
                                                    const float* __restrict__ feats,
                                                    float* __restrict__ part) { // [96][32][1536]
    const int bid = blockIdx.x;
    const int ks = bid & 31;
    const int nb = bid >> 5;
    const int tid = threadIdx.x;

    __shared__ float alds[2][NST * NC * 4];   // [kkg][96] float4 slots
    __shared__ float blds[2][NST * BN8 * 4];  // [kkg][96] float4 slots

    const int j0 = nb * BN8;
    const int k0b = ks * KCH;

    const int tx = tid & 15;         // n = tx + 16*nn, nn 0..5
    const int ty = tid >> 4;         // m = ty*6 + mi, mi 0..5
    const int m0 = ty * 6;

    // per-lane DMA source mapping (only k0 varies per stage)
    // slots s = tid + i*256, s = kkg*96 + row
    const float* aga[3];
    const float* bga[3];
    int lbase[3];
#pragma unroll
    for (int i = 0; i < 3; ++i) {
        const int s = tid + i * 256;
        const int kkg = s / NC, r = s - kkg * NC;
        aga[i] = centers + (size_t)r * FD + kkg * 4;
        bga[i] = feats + (size_t)(j0 + r) * FD + kkg * 4;
        lbase[i] = (i * 256 + (tid & 192)) * 4;   // float offset of wave chunk
    }

    // prologue: stage 0 -> buf 0
#pragma unroll
    for (int i = 0; i < 3; ++i) gload16(aga[i] + k0b, &alds[0][lbase[i]]);
#pragma unroll
    for (int i = 0; i < 3; ++i) gload16(bga[i] + k0b, &blds[0][lbase[i]]);
    __syncthreads();

    float acc[6][6];
#pragma unroll
    for (int a = 0; a < 6; ++a)
#pragma unroll
        for (int b = 0; b < 6; ++b) acc[a][b] = 0.f;

    int cur = 0;
    for (int st = 0; st < NST; ++st) {
        // issue next stage's DMA into the other buffer; flies during compute
        if (st < NST - 1) {
            const int k0 = k0b + (st + 1) * BKS;
#pragma unroll
            for (int i = 0; i < 3; ++i) gload16(aga[i] + k0, &alds[cur ^ 1][lbase[i]]);
#pragma unroll
            for (int i = 0; i < 3; ++i) gload16(bga[i] + k0, &blds[cur ^ 1][lbase[i]]);
        }

        // compute current buffer: k-group-major, conflict-free reads
#pragma unroll
        for (int kg = 0; kg < NST; ++kg) {
            const float* ab = &alds[cur][kg * (NC * 4)];
            const float* bb = &blds[cur][kg * (BN8 * 4)];
            float4 bv[6];
#pragma unroll
            for (int nn = 0; nn < 6; ++nn)
                bv[nn] = *(const float4*)&bb[(tx + nn * 16) * 4];
#pragma unroll
            for (int mi = 0; mi < 6; ++mi) {
                const float4 a = *(const float4*)&ab[(m0 + mi) * 4];
#pragma unroll
                for (int nn = 0; nn < 6; ++nn)
                    acc[mi][nn] += a.x * bv[nn].x + a.y * bv[nn].y +
                                   a.z * bv[nn].z + a.w * bv[nn].w;
            }
        }
        __syncthreads();   // drains vmcnt -> next buffer ready
        cur ^= 1;
    }

#pragma unroll
    for (int mi = 0; mi < 6; ++mi) {
        float* row = part + ((size_t)(m0 + mi) * KSPLIT + ks) * M_ROWS + j0;
#pragma unroll
        for (int nn = 0; nn < 6; ++nn)
            row[tx + nn * 16] = acc[mi][nn];
    }
}

// ---------------- K3: finalize d2 + masked argmax/argmin ----------------
__global__ void select_kernel(const float* __restrict__ part,
                              const float* __restrict__ fnp,
                              const float* __restrict__ cnp,
                              const int* __restrict__ labels,
                              int* __restrict__ pinds,
                              int* __restrict__ ninds) {
    const int c = blockIdx.x;
    const int tid = threadIdx.x;
    const int anchor = labels[c * KG];

    float cn = 0.f;
#pragma unroll
    for (int b = 0; b < 4; ++b) cn += cnp[b * NC + c];

    float bestp = -INFINITY; int bpi = 1 << 30;
    float bestn =  INFINITY; int bni = 1 << 30;

    const float* pc = part + (size_t)c * KSPLIT * M_ROWS;
    for (int j = tid; j < M_ROWS; j += 256) {
        float dot = 0.f;
#pragma unroll
        for (int p = 0; p < KSPLIT; ++p)
            dot += pc[(size_t)p * M_ROWS + j];
        float fn = 0.f;
#pragma unroll
        for (int b = 0; b < 4; ++b) fn += fnp[b * M_ROWS + j];
        const float d2 = cn + fn - 2.f * dot;
        const bool pos = (labels[j] == anchor);
        if (pos) {
            if (d2 > bestp || (d2 == bestp && j < bpi)) { bestp = d2; bpi = j; }
        } else {
            if (d2 < bestn || (d2 == bestn && j < bni)) { bestn = d2; bni = j; }
        }
    }

    __shared__ float sv[256];
    __shared__ int   si[256];
    sv[tid] = bestp; si[tid] = bpi; __syncthreads();
    for (int s = 128; s > 0; s >>= 1) {
        if (tid < s) {
            if (sv[tid + s] > sv[tid] ||
                (sv[tid + s] == sv[tid] && si[tid + s] < si[tid])) {
                sv[tid] = sv[tid + s]; si[tid] = si[tid + s];
            }
        }
        __syncthreads();
    }
    if (tid == 0) pinds[c] = si[0];
    __syncthreads();
    sv[tid] = bestn; si[tid] = bni; __syncthreads();
    for (int s = 128; s > 0; s >>= 1) {
        if (tid < s) {
            if (sv[tid + s] < sv[tid] ||
                (sv[tid + s] == sv[tid] && si[tid + s] < si[tid])) {
                sv[tid] = sv[tid + s]; si[tid] = si[tid + s];
            }
        }
        __syncthreads();
    }
    if (tid == 0) ninds[c] = si[0];
}

// ---------------- K4: local stripe distances + DP ----------------
__global__ void local_kernel(const float* __restrict__ centers,
                             const float* __restrict__ localf,
                             const int* __restrict__ pinds,
                             const int* __restrict__ ninds,
                             float* __restrict__ res) { // [2][96]
    const int c = blockIdx.x;
    const int which = blockIdx.y;
    const int tid = threadIdx.x;
    const int idx = (which == 0) ? pinds[c] : ninds[c];

    __shared__ float xl[NS * 1028];
    __shared__ float yl[NS * 1032];
    __shared__ float sred[256];
    __shared__ float dmat[64];
    __shared__ float xx[8], yy[8], xyv[64];

#pragma unroll
    for (int it = 0; it < 8; ++it) {
        const int q = tid + it * 256;
        const float4 v = *(const float4*)&centers[(size_t)c * FD + q * 4];
        const int i = q >> 8;
        const int d = (q * 4) & 1023;
        *(float4*)&xl[i * 1028 + d] = v;

        const float4 w = *(const float4*)&localf[(size_t)idx * FD + q * 4];
        const int jb = (q * 4) & 7;
        const int dd = q >> 1;
        yl[(jb + 0) * 1032 + dd] = w.x;
        yl[(jb + 1) * 1032 + dd] = w.y;
        yl[(jb + 2) * 1032 + dd] = w.z;
        yl[(jb + 3) * 1032 + dd] = w.w;
    }
    __syncthreads();

    const int p = tid >> 2, c4 = tid & 3;
    const int i = p >> 3, j = p & 7;
    float s = 0.f;
    for (int t = 0; t < 64; ++t) {
        const int d = c4 * 4 + t * 16;
        const float4 xv = *(const float4*)&xl[i * 1028 + d];
        const float4 yv = *(const float4*)&yl[j * 1032 + d];
        s += xv.x * yv.x + xv.y * yv.y + xv.z * yv.z + xv.w * yv.w;
    }
    sred[tid] = s;
    __syncthreads();
    if (tid < 64)
        xyv[tid] = sred[tid * 4] + sred[tid * 4 + 1] + sred[tid * 4 + 2] + sred[tid * 4 + 3];

    float s2 = 0.f;
    if (tid < 64) {
        const int r = tid >> 2;
        const float* base = (r < 8) ? &xl[r * 1028] : &yl[(r - 8) * 1032];
        for (int t = 0; t < 64; ++t) {
            const int d = c4 * 4 + t * 16;
            const float4 v = *(const float4*)&base[d];
            s2 += v.x * v.x + v.y * v.y + v.z * v.z + v.w * v.w;
        }
    }
    __syncthreads();
    sred[tid] = s2;
    __syncthreads();
    if (tid < 16) {
        const float v = sred[tid * 4] + sred[tid * 4 + 1] + sred[tid * 4 + 2] + sred[tid * 4 + 3];
        if (tid < 8) xx[tid] = v; else yy[tid - 8] = v;
    }
    __syncthreads();

    if (tid < 64) {
        const float d2 = xx[i] + yy[j] - 2.f * xyv[tid];
        const float d = sqrtf(fmaxf(d2, 1e-12f));
        dmat[tid] = tanhf(0.5f * d);
    }
    __syncthreads();

    if (tid == 0) {
        float prev[8], cur[8];
        cur[0] = dmat[0];
#pragma unroll
        for (int jj = 1; jj < 8; ++jj) cur[jj] = cur[jj - 1] + dmat[jj];
        for (int ii = 1; ii < 8; ++ii) {
#pragma unroll
            for (int jj = 0; jj < 8; ++jj) prev[jj] = cur[jj];
            cur[0] = prev[0] + dmat[ii * 8];
#pragma unroll
            for (int jj = 1; jj < 8; ++jj)
                cur[jj] = fminf(prev[jj], cur[jj - 1]) + dmat[ii * 8 + jj];
        }
        res[which * NC + c] = cur[7];
    }
}

// ---------------- K5: mean(relu(ap - an + margin)) ----------------
__global__ void loss_kernel(const float* __restrict__ res, float* __restrict__ out) {
    const int tid = threadIdx.x; // 128
    float v = 0.f;
    if (tid < NC) v = fmaxf(res[tid] - res[NC + tid] + MARGIN, 0.f);
#pragma unroll
    for (int off = 32; off > 0; off >>= 1) v += __shfl_down(v, off, 64);
    __shared__ float w2[2];
    const int lane = tid & 63, w = tid >> 6;
    if (lane == 0) w2[w] = v;
    __syncthreads();
    if (tid == 0) out[0] = (w2[0] + w2[1]) * (1.f / NC);
}

extern "C" void kernel_launch(void* const* d_in, const int* in_sizes, int n_in,
                              void* d_out, int out_size, void* d_ws, size_t ws_size,
                              hipStream_t stream) {
    const float* feats  = (const float*)d_in[0];
    const int*   labels = (const int*)d_in[1];
    const float* localf = (const float*)d_in[2];
    float* out = (float*)d_out;

    float* centers = (float*)d_ws;                          // 96*8192
    float* part    = centers + (size_t)NC * FD;             // 96*32*1536
    float* fnp     = part + (size_t)NC * KSPLIT * M_ROWS;   // 4*1536
    float* cnp     = fnp + 4 * M_ROWS;                      // 4*96
    float* res     = cnp + 4 * NC;                          // 2*96
    int*   pinds   = (int*)(res + 2 * NC);                  // 96
    int*   ninds   = pinds + NC;                            // 96

    hipLaunchKernelGGL(centers_kernel, dim3(NC, 4), dim3(256), 0, stream,
                       feats, centers, fnp, cnp);
    hipLaunchKernelGGL(gemm8_kernel, dim3(16 * KSPLIT), dim3(256), 0, stream,
                       centers, feats, part);
    hipLaunchKernelGGL(select_kernel, dim3(NC), dim3(256), 0, stream,
                       part, fnp, cnp, labels, pinds, ninds);
    hipLaunchKernelGGL(local_kernel, dim3(NC, 2), dim3(256), 0, stream,
                       centers, localf, pinds, ninds, res);
    hipLaunchKernelGGL(loss_kernel, dim3(1), dim3(128), 0, stream, res, out);
}